// Round 1
// baseline (54302.960 us; speedup 1.0000x reference)
//
#include <hip/hip_runtime.h>
#include <cstddef>

static constexpr float LCA_LAMBDA = 0.5f;
static constexpr float LCA_ETA    = 1.0f / 1000.0f;

// ---------------------------------------------------------------- utilities

__global__ void zero_kernel(float* __restrict__ p, int n) {
  int i = blockIdx.x * blockDim.x + threadIdx.x;
  if (i < n) p[i] = 0.f;
}

// per-sample standardize over C*H*W (population std, eps 1e-8 on std)
__global__ __launch_bounds__(256) void standardize_kernel(
    const float* __restrict__ in, float* __restrict__ out, int CHW) {
  int n = blockIdx.x;
  const float* src = in + (size_t)n * CHW;
  float* dst = out + (size_t)n * CHW;
  int t = threadIdx.x;
  float s = 0.f, ss = 0.f;
  for (int i = t; i < CHW; i += 256) { float v = src[i]; s += v; ss += v * v; }
  __shared__ float red0[256], red1[256];
  red0[t] = s; red1[t] = ss;
  __syncthreads();
  for (int off = 128; off > 0; off >>= 1) {
    if (t < off) { red0[t] += red0[t + off]; red1[t] += red1[t + off]; }
    __syncthreads();
  }
  float m = red0[0] / (float)CHW;
  float var = red1[0] / (float)CHW - m * m;
  var = fmaxf(var, 0.f);
  float inv = 1.0f / (sqrtf(var) + 1e-8f);
  for (int i = t; i < CHW; i += 256) dst[i] = (src[i] - m) * inv;
}

// BatchNorm2d training-mode math over (N,H,W) per channel; optional input
// transform a=relu(u-lambda) (used to read LCA's final u directly).
template <bool TRANSFORM>
__global__ __launch_bounds__(256) void bn_kernel(
    const float* __restrict__ in, float* __restrict__ out,
    const float* __restrict__ gamma, const float* __restrict__ beta,
    int C, int HW, int N) {
  int c = blockIdx.x;
  int t = threadIdx.x;
  float s = 0.f, ss = 0.f;
  for (int n = 0; n < N; ++n) {
    const float* src = in + ((size_t)n * C + c) * HW;
    for (int i = t; i < HW; i += 256) {
      float v = src[i];
      if (TRANSFORM) v = fmaxf(v - LCA_LAMBDA, 0.f);
      s += v; ss += v * v;
    }
  }
  __shared__ float red0[256], red1[256];
  red0[t] = s; red1[t] = ss;
  __syncthreads();
  for (int off = 128; off > 0; off >>= 1) {
    if (t < off) { red0[t] += red0[t + off]; red1[t] += red1[t + off]; }
    __syncthreads();
  }
  float cnt = (float)(N * HW);
  float m = red0[0] / cnt;
  float var = red1[0] / cnt - m * m;
  var = fmaxf(var, 0.f);
  float scale = gamma[c] * rsqrtf(var + 1e-5f);
  float shift = beta[c] - m * scale;
  for (int n = 0; n < N; ++n) {
    const float* src = in + ((size_t)n * C + c) * HW;
    float* dst = out + ((size_t)n * C + c) * HW;
    for (int i = t; i < HW; i += 256) {
      float v = src[i];
      if (TRANSFORM) v = fmaxf(v - LCA_LAMBDA, 0.f);
      dst[i] = v * scale + shift;
    }
  }
}

// Feature Gram kernel G[i][j][p][q] = sum_{c,ky,kx} w[i,c,p+ky-4,q+kx-4]*w[j,c,ky,kx]
// stored padded: Gp[i][j][p][12] (q 0..8 valid, 9..11 zero) for float4 loads.
__global__ void gram_kernel(const float* __restrict__ w, float* __restrict__ Gp,
                            int F, int Cin) {
  int idx = blockIdx.x * blockDim.x + threadIdx.x;
  int tot = F * F * 9 * 12;
  if (idx >= tot) return;
  int q = idx % 12;
  int p = (idx / 12) % 9;
  int j = (idx / 108) % F;
  int i = idx / (108 * F);
  float acc = 0.f;
  if (q < 9) {
    int ky0 = max(0, 4 - p), ky1 = min(4, 8 - p);
    int kx0 = max(0, 4 - q), kx1 = min(4, 8 - q);
    for (int c = 0; c < Cin; ++c) {
      const float* wi = w + ((size_t)i * Cin + c) * 25;
      const float* wj = w + ((size_t)j * Cin + c) * 25;
      for (int ky = ky0; ky <= ky1; ++ky)
        for (int kx = kx0; kx <= kx1; ++kx)
          acc += wi[(p + ky - 4) * 5 + (q + kx - 4)] * wj[ky * 5 + kx];
    }
  }
  Gp[idx] = acc;
}

// generic 5x5 pad-2 cross-correlation (NCHW / OIHW), optional bias+relu
__global__ void conv5x5_kernel(const float* __restrict__ in,
                               const float* __restrict__ w,
                               const float* __restrict__ bias,
                               float* __restrict__ out,
                               int N, int Ci, int Co, int H, int W, int do_relu) {
  int idx = blockIdx.x * blockDim.x + threadIdx.x;
  int tot = N * Co * H * W;
  if (idx >= tot) return;
  int x = idx % W;
  int y = (idx / W) % H;
  int co = (idx / (W * H)) % Co;
  int n = idx / (W * H * Co);
  float acc = bias ? bias[co] : 0.f;
  for (int c = 0; c < Ci; ++c) {
    const float* ip = in + ((size_t)n * Ci + c) * H * W;
    const float* wp = w + ((size_t)co * Ci + c) * 25;
#pragma unroll
    for (int ky = 0; ky < 5; ++ky) {
      int yy = y + ky - 2;
      if (yy < 0 || yy >= H) continue;
#pragma unroll
      for (int kx = 0; kx < 5; ++kx) {
        int xx = x + kx - 2;
        if (xx < 0 || xx >= W) continue;
        acc = fmaf(ip[yy * W + xx], wp[ky * 5 + kx], acc);
      }
    }
  }
  if (do_relu) acc = fmaxf(acc, 0.f);
  out[idx] = acc;
}

template <bool TRANSFORM>
__global__ void maxpool_kernel(const float* __restrict__ in, float* __restrict__ out,
                               int N, int C, int Ho, int Wo) {
  int idx = blockIdx.x * blockDim.x + threadIdx.x;
  int tot = N * C * Ho * Wo;
  if (idx >= tot) return;
  int x = idx % Wo;
  int y = (idx / Wo) % Ho;
  int c = (idx / (Wo * Ho)) % C;
  int n = idx / (Wo * Ho * C);
  int H = Ho * 2, W = Wo * 2;
  const float* ip = in + (((size_t)n * C + c) * H + 2 * y) * W + 2 * x;
  float v0 = ip[0], v1 = ip[1], v2 = ip[W], v3 = ip[W + 1];
  if (TRANSFORM) {
    v0 = fmaxf(v0 - LCA_LAMBDA, 0.f);
    v1 = fmaxf(v1 - LCA_LAMBDA, 0.f);
    v2 = fmaxf(v2 - LCA_LAMBDA, 0.f);
    v3 = fmaxf(v3 - LCA_LAMBDA, 0.f);
  }
  out[idx] = fmaxf(fmaxf(v0, v1), fmaxf(v2, v3));
}

template <bool RELU>
__global__ __launch_bounds__(64) void fc_kernel(
    const float* __restrict__ in, const float* __restrict__ w,
    const float* __restrict__ bias, float* __restrict__ out, int K) {
  int o = blockIdx.x;   // output feature
  int n = blockIdx.y;   // sample
  int Osz = gridDim.x;
  const float* ip = in + (size_t)n * K;
  const float* wp = w + (size_t)o * K;
  float s = 0.f;
  for (int k = threadIdx.x; k < K; k += 64) s = fmaf(ip[k], wp[k], s);
  for (int off = 32; off > 0; off >>= 1) s += __shfl_down(s, off, 64);
  if (threadIdx.x == 0) {
    s += bias[o];
    if (RELU) s = fmaxf(s, 0.f);
    out[(size_t)n * Osz + o] = s;
  }
}

// ------------------------------------------------------------- LCA iteration
// One step: a = relu(u-l); u' = u + eta*(drive - u - conv(a,G) + a)
// Block: 64 threads = 8 x-groups (4 consecutive x each) x 8 features.
// Grid: (C/8 f-groups, 32 rows, 4 samples). LDS slab holds a for rows
// y-4..y+4 (x padded to 40). Slab addresses depend only on xg -> 8-lane
// broadcast, conflict-free b128 reads; 36 FMA per 3 LDS reads.
template <int C>
__global__ __launch_bounds__(64) void lca_step_kernel(
    const float* __restrict__ u_in, float* __restrict__ u_out,
    const float* __restrict__ drive, const float* __restrict__ Gp) {
  __shared__ float slab[9 * C * 40];  // [p][g][40]
  const int t = threadIdx.x;
  const int fg = blockIdx.x;
  const int y = blockIdx.y;
  const int n = blockIdx.z;

  const float* ub = u_in + (size_t)n * C * 1024;
  const int TOT = 9 * C * 40;
  for (int idx = t; idx < TOT; idx += 64) {
    int xs_ = idx % 40;
    int rest = idx / 40;
    int g = rest % C;
    int p = rest / C;
    int yy = y + p - 4;
    int xx = xs_ - 4;
    float v = 0.f;
    if (yy >= 0 && yy < 32 && xx >= 0 && xx < 32)
      v = fmaxf(ub[(g * 32 + yy) * 32 + xx] - LCA_LAMBDA, 0.f);
    slab[idx] = v;
  }
  __syncthreads();

  const int xg = t & 7, x0 = xg * 4;
  const int f = fg * 8 + (t >> 3);

  float acc0 = 0.f, acc1 = 0.f, acc2 = 0.f, acc3 = 0.f;
  const float4* gbase = (const float4*)Gp + (size_t)f * C * 27;  // [f][g][p][12]
  for (int g = 0; g < C; ++g) {
    const float* srow = &slab[g * 40 + x0];
    const float4* grow = gbase + g * 27;
#pragma unroll
    for (int p = 0; p < 9; ++p) {
      const float* s = srow + p * (C * 40);
      float4 a0 = *(const float4*)(s);
      float4 a1 = *(const float4*)(s + 4);
      float4 a2 = *(const float4*)(s + 8);
      float4 g0 = grow[p * 3], g1 = grow[p * 3 + 1], g2 = grow[p * 3 + 2];
      float wv[12] = {a0.x, a0.y, a0.z, a0.w, a1.x, a1.y,
                      a1.z, a1.w, a2.x, a2.y, a2.z, a2.w};
      float gv[9] = {g0.x, g0.y, g0.z, g0.w, g1.x, g1.y, g1.z, g1.w, g2.x};
#pragma unroll
      for (int q = 0; q < 9; ++q) {
        acc0 = fmaf(wv[q + 0], gv[q], acc0);
        acc1 = fmaf(wv[q + 1], gv[q], acc1);
        acc2 = fmaf(wv[q + 2], gv[q], acc2);
        acc3 = fmaf(wv[q + 3], gv[q], acc3);
      }
    }
  }

  size_t o = (((size_t)n * C + f) * 32 + y) * 32 + x0;
  float4 uo = *(const float4*)(u_in + o);
  float4 dv = *(const float4*)(drive + o);
  float4 r;
  float a;
  a = fmaxf(uo.x - LCA_LAMBDA, 0.f);
  r.x = uo.x + LCA_ETA * (dv.x - uo.x - acc0 + a);
  a = fmaxf(uo.y - LCA_LAMBDA, 0.f);
  r.y = uo.y + LCA_ETA * (dv.y - uo.y - acc1 + a);
  a = fmaxf(uo.z - LCA_LAMBDA, 0.f);
  r.z = uo.z + LCA_ETA * (dv.z - uo.z - acc2 + a);
  a = fmaxf(uo.w - LCA_LAMBDA, 0.f);
  r.w = uo.w + LCA_ETA * (dv.w - uo.w - acc3 + a);
  *(float4*)(u_out + o) = r;
}

// ------------------------------------------------------------------ launcher

extern "C" void kernel_launch(void* const* d_in, const int* in_sizes, int n_in,
                              void* d_out, int out_size, void* d_ws, size_t ws_size,
                              hipStream_t stream) {
  const float* x       = (const float*)d_in[0];
  const float* w_lca1  = (const float*)d_in[1];
  const float* w_lca2  = (const float*)d_in[2];
  const float* bn1_g   = (const float*)d_in[3];
  const float* bn1_b   = (const float*)d_in[4];
  const float* bn2_g   = (const float*)d_in[5];
  const float* bn2_b   = (const float*)d_in[6];
  const float* w_conv1 = (const float*)d_in[7];
  const float* b_conv1 = (const float*)d_in[8];
  const float* bn3_g   = (const float*)d_in[9];
  const float* bn3_b   = (const float*)d_in[10];
  const float* w_conv2 = (const float*)d_in[11];
  const float* b_conv2 = (const float*)d_in[12];
  const float* bn4_g   = (const float*)d_in[13];
  const float* bn4_b   = (const float*)d_in[14];
  const float* w_conv3 = (const float*)d_in[15];
  const float* b_conv3 = (const float*)d_in[16];
  const float* bn5_g   = (const float*)d_in[17];
  const float* bn5_b   = (const float*)d_in[18];
  const float* w_fc1   = (const float*)d_in[19];
  const float* b_fc1   = (const float*)d_in[20];
  const float* w_fc2   = (const float*)d_in[21];
  const float* b_fc2   = (const float*)d_in[22];
  float* outp = (float*)d_out;

  float* ws = (float*)d_ws;
  size_t off = 0;
  auto alloc = [&](size_t nelem) {
    float* p = ws + off;
    off += (nelem + 63) & ~(size_t)63;
    return p;
  };
  float* xs     = alloc(4 * 3 * 32 * 32);
  float* Gp1    = alloc(16 * 16 * 9 * 12);
  float* Gp2    = alloc(32 * 32 * 9 * 12);
  float* drive1 = alloc(65536);
  float* uA1    = alloc(65536);
  float* uB1    = alloc(65536);
  float* h1     = alloc(65536);
  float* h1s    = alloc(65536);
  float* drive2 = alloc(131072);
  float* uA2    = alloc(131072);
  float* uB2    = alloc(131072);
  float* p0     = alloc(32768);
  float* b0     = alloc(32768);
  float* c1     = alloc(65536);
  float* p1     = alloc(16384);
  float* bb1    = alloc(16384);
  float* c2     = alloc(32768);
  float* p2     = alloc(8192);
  float* bb2    = alloc(8192);
  float* c3     = alloc(16384);
  float* p3     = alloc(4096);
  float* bb3    = alloc(4096);
  float* f1     = alloc(2048);

  // ---- LCA1 setup
  standardize_kernel<<<4, 256, 0, stream>>>(x, xs, 3 * 32 * 32);
  { int tot = 16 * 16 * 108;
    gram_kernel<<<(tot + 255) / 256, 256, 0, stream>>>(w_lca1, Gp1, 16, 3); }
  { int tot = 32 * 32 * 108;
    gram_kernel<<<(tot + 255) / 256, 256, 0, stream>>>(w_lca2, Gp2, 32, 16); }
  conv5x5_kernel<<<(65536 + 255) / 256, 256, 0, stream>>>(
      xs, w_lca1, nullptr, drive1, 4, 3, 16, 32, 32, 0);
  zero_kernel<<<(65536 + 255) / 256, 256, 0, stream>>>(uA1, 65536);

  // ---- LCA1 iterations (500)
  {
    dim3 grid(2, 32, 4);
    float* uin = uA1;
    float* uout = uB1;
    for (int it = 0; it < 500; ++it) {
      lca_step_kernel<16><<<grid, 64, 0, stream>>>(uin, uout, drive1, Gp1);
      float* tmp = uin; uin = uout; uout = tmp;
    }
    // a1 = relu(u-l) folded into BN1's transform
    bn_kernel<true><<<16, 256, 0, stream>>>(uin, h1, bn1_g, bn1_b, 16, 1024, 4);
  }

  // ---- LCA2 setup
  standardize_kernel<<<4, 256, 0, stream>>>(h1, h1s, 16 * 32 * 32);
  conv5x5_kernel<<<(131072 + 255) / 256, 256, 0, stream>>>(
      h1s, w_lca2, nullptr, drive2, 4, 16, 32, 32, 32, 0);
  zero_kernel<<<(131072 + 255) / 256, 256, 0, stream>>>(uA2, 131072);

  // ---- LCA2 iterations (500)
  {
    dim3 grid(4, 32, 4);
    float* uin = uA2;
    float* uout = uB2;
    for (int it = 0; it < 500; ++it) {
      lca_step_kernel<32><<<grid, 64, 0, stream>>>(uin, uout, drive2, Gp2);
      float* tmp = uin; uin = uout; uout = tmp;
    }
    // a2 = relu(u-l) folded into pool transform
    maxpool_kernel<true><<<(32768 + 255) / 256, 256, 0, stream>>>(uin, p0, 4, 32, 16, 16);
  }
  bn_kernel<false><<<32, 256, 0, stream>>>(p0, b0, bn2_g, bn2_b, 32, 256, 4);

  // ---- conv tail
  conv5x5_kernel<<<(65536 + 255) / 256, 256, 0, stream>>>(
      b0, w_conv1, b_conv1, c1, 4, 32, 64, 16, 16, 1);
  maxpool_kernel<false><<<(16384 + 255) / 256, 256, 0, stream>>>(c1, p1, 4, 64, 8, 8);
  bn_kernel<false><<<64, 256, 0, stream>>>(p1, bb1, bn3_g, bn3_b, 64, 64, 4);

  conv5x5_kernel<<<(32768 + 255) / 256, 256, 0, stream>>>(
      bb1, w_conv2, b_conv2, c2, 4, 64, 128, 8, 8, 1);
  maxpool_kernel<false><<<(8192 + 255) / 256, 256, 0, stream>>>(c2, p2, 4, 128, 4, 4);
  bn_kernel<false><<<128, 256, 0, stream>>>(p2, bb2, bn4_g, bn4_b, 128, 16, 4);

  conv5x5_kernel<<<(16384 + 255) / 256, 256, 0, stream>>>(
      bb2, w_conv3, b_conv3, c3, 4, 128, 256, 4, 4, 1);
  maxpool_kernel<false><<<(4096 + 255) / 256, 256, 0, stream>>>(c3, p3, 4, 256, 2, 2);
  bn_kernel<false><<<256, 256, 0, stream>>>(p3, bb3, bn5_g, bn5_b, 256, 4, 4);

  // ---- FC head
  fc_kernel<true><<<dim3(512, 4), 64, 0, stream>>>(bb3, w_fc1, b_fc1, f1, 1024);
  fc_kernel<false><<<dim3(10, 4), 64, 0, stream>>>(f1, w_fc2, b_fc2, outp, 512);

  (void)in_sizes; (void)n_in; (void)out_size; (void)ws_size;
}